// Round 3
// baseline (543.008 us; speedup 1.0000x reference)
//
#include <hip/hip_runtime.h>
#include <math.h>

#define BS  256
#define SEQ 512
#define H   768

// ---------------- Threefry-2x32-20, key = (0, 42) -- matches JAX exactly ---
__device__ __forceinline__ unsigned rotl32(unsigned x, int r) {
  return (x << r) | (x >> (32 - r));
}

__device__ __forceinline__ void threefry_0_42(unsigned& x0, unsigned& x1) {
  const unsigned ks0 = 0u;
  const unsigned ks1 = 42u;
  const unsigned ks2 = ks0 ^ ks1 ^ 0x1BD11BDAu;
  x0 += ks0; x1 += ks1;
#define TF_ROUND(r) { x0 += x1; x1 = rotl32(x1, (r)); x1 ^= x0; }
  TF_ROUND(13) TF_ROUND(15) TF_ROUND(26) TF_ROUND(6)
  x0 += ks1; x1 += ks2 + 1u;
  TF_ROUND(17) TF_ROUND(29) TF_ROUND(16) TF_ROUND(24)
  x0 += ks2; x1 += ks0 + 2u;
  TF_ROUND(13) TF_ROUND(15) TF_ROUND(26) TF_ROUND(6)
  x0 += ks0; x1 += ks1 + 3u;
  TF_ROUND(17) TF_ROUND(29) TF_ROUND(16) TF_ROUND(24)
  x0 += ks1; x1 += ks2 + 4u;
  TF_ROUND(13) TF_ROUND(15) TF_ROUND(26) TF_ROUND(6)
  x0 += ks2; x1 += ks0 + 5u;
#undef TF_ROUND
}

// One block per batch row. 768 threads = one per hidden column.
// No workspace: everything lives in LDS / registers, writes only d_out.
__global__ __launch_bounds__(768) void fused_kernel(
    const float* __restrict__ tokens,   // [BS, SEQ, H]
    const float* __restrict__ cls,      // [BS, H]
    const int*   __restrict__ mask,     // [BS, SEQ]
    const float* __restrict__ W,        // [2H, H] row-major
    const float* __restrict__ bias,     // [H]
    const float* __restrict__ v,        // [H]
    float* __restrict__ out)            // [BS, H]
{
  const int b = blockIdx.x;
  const int t = threadIdx.x;            // 0..767  == output column j

  __shared__ float s_cls[H];
  __shared__ float s_emb[H];
  __shared__ int   s_len;
  __shared__ float r0[12], r1[12];
  __shared__ float s_alpha[2];

  if (t == 0) s_len = SEQ;
  __syncthreads();

  // length = index of first zero (number of leading ones); 512 threads scan
  if (t < SEQ) {
    if (mask[b * SEQ + t] == 0) atomicMin(&s_len, t);
  }
  __syncthreads();
  const int len = s_len;
  const float lenf = (float)len;

  // Threefry sample + gather.
  // JAX >= 0.4.27 default: jax_threefry_partitionable=True. Per-element
  // 64-bit counter c = n; threefry inputs (hi32(c), lo32(c)) = (0, n);
  // 32-bit output = out0 ^ out1.
  {
    const unsigned n = (unsigned)(b * H + t);
    unsigned x0 = 0u, x1 = n;
    threefry_0_42(x0, x1);
    const unsigned bits = x0 ^ x1;
    const float u = __uint_as_float((bits >> 9) | 0x3f800000u) - 1.0f;
    int idx = (int)floorf(u * lenf);
    idx = min(idx, len - 1);
    s_cls[t] = cls[b * H + t];
    s_emb[t] = tokens[(size_t)b * (SEQ * H) + (size_t)idx * H + t];
  }
  __syncthreads();

  // GEMV: T = cls@Wtop[:,t], U0 = cls@Wbot[:,t], U1 = emb@Wbot[:,t]
  float accT = 0.0f, accU0 = 0.0f, accU1 = 0.0f;
  const float* __restrict__ Wt = W;
  const float* __restrict__ Wb = W + (size_t)H * H;
#pragma unroll 4
  for (int i = 0; i < H; ++i) {
    const float c = s_cls[i];
    const float e = s_emb[i];
    const float wt = Wt[(size_t)i * H + t];
    const float wb = Wb[(size_t)i * H + t];
    accT  = fmaf(c, wt, accT);
    accU0 = fmaf(c, wb, accU0);
    accU1 = fmaf(e, wb, accU1);
  }

  const float bb = bias[t];
  const float vv = v[t];
  float s0 = vv * tanhf(accT + accU0 + bb);
  float s1 = vv * tanhf(accT + accU1 + bb);

  // reduce across 768 threads (12 waves)
#pragma unroll
  for (int off = 32; off > 0; off >>= 1) {
    s0 += __shfl_down(s0, off);
    s1 += __shfl_down(s1, off);
  }
  const int w = t >> 6, lane = t & 63;
  if (lane == 0) { r0[w] = s0; r1[w] = s1; }
  __syncthreads();
  if (t == 0) {
    float e0 = 0.0f, e1 = 0.0f;
#pragma unroll
    for (int k = 0; k < 12; ++k) { e0 += r0[k]; e1 += r1[k]; }
    const float mx = fmaxf(e0, e1);
    const float x0 = expf(e0 - mx), x1 = expf(e1 - mx);
    const float inv = 1.0f / (x0 + x1);
    s_alpha[0] = x0 * inv; s_alpha[1] = x1 * inv;
  }
  __syncthreads();

  out[b * H + t] = s_alpha[0] * s_cls[t] + s_alpha[1] * s_emb[t];
}

// ---------------------------------------------------------------------------
extern "C" void kernel_launch(void* const* d_in, const int* in_sizes, int n_in,
                              void* d_out, int out_size, void* d_ws, size_t ws_size,
                              hipStream_t stream) {
  const float* tokens = (const float*)d_in[0];   // [256,512,768] f32
  const float* cls    = (const float*)d_in[1];   // [256,768] f32
  const int*   mask   = (const int*)  d_in[2];   // [256,512] i32
  const float* W      = (const float*)d_in[3];   // [1536,768] f32
  const float* bias   = (const float*)d_in[4];   // [768] f32
  const float* v      = (const float*)d_in[5];   // [768] f32
  float* out = (float*)d_out;

  fused_kernel<<<BS, 768, 0, stream>>>(tokens, cls, mask, W, bias, v, out);
}

// Round 4
// 495.356 us; speedup vs baseline: 1.0962x; 1.0962x over previous
//
#include <hip/hip_runtime.h>
#include <math.h>

#define BS  256
#define SEQ 512
#define H   768

// ---------------- Threefry-2x32-20, key = (0, 42) -- matches JAX exactly ---
// (partitionable path: inputs (0, n), 32-bit output = out0 ^ out1)
__device__ __forceinline__ unsigned rotl32(unsigned x, int r) {
  return (x << r) | (x >> (32 - r));
}

__device__ __forceinline__ void threefry_0_42(unsigned& x0, unsigned& x1) {
  const unsigned ks0 = 0u;
  const unsigned ks1 = 42u;
  const unsigned ks2 = ks0 ^ ks1 ^ 0x1BD11BDAu;
  x0 += ks0; x1 += ks1;
#define TF_ROUND(r) { x0 += x1; x1 = rotl32(x1, (r)); x1 ^= x0; }
  TF_ROUND(13) TF_ROUND(15) TF_ROUND(26) TF_ROUND(6)
  x0 += ks1; x1 += ks2 + 1u;
  TF_ROUND(17) TF_ROUND(29) TF_ROUND(16) TF_ROUND(24)
  x0 += ks2; x1 += ks0 + 2u;
  TF_ROUND(13) TF_ROUND(15) TF_ROUND(26) TF_ROUND(6)
  x0 += ks0; x1 += ks1 + 3u;
  TF_ROUND(17) TF_ROUND(29) TF_ROUND(16) TF_ROUND(24)
  x0 += ks1; x1 += ks2 + 4u;
  TF_ROUND(13) TF_ROUND(15) TF_ROUND(26) TF_ROUND(6)
  x0 += ks2; x1 += ks0 + 5u;
#undef TF_ROUND
}

// ---------------- Kernel 1: length + sample + gather; zero energy accs ----
__global__ __launch_bounds__(256) void prep_kernel(
    const float* __restrict__ tokens,   // [BS, SEQ, H]
    const int*   __restrict__ mask,     // [BS, SEQ]
    float* __restrict__ emb,            // [BS, H] out (ws)
    float* __restrict__ ge0,            // [BS] zeroed
    float* __restrict__ ge1)            // [BS] zeroed
{
  const int b = blockIdx.x;
  const int t = threadIdx.x;

  __shared__ int s_len;
  if (t == 0) { s_len = SEQ; ge0[b] = 0.0f; ge1[b] = 0.0f; }
  __syncthreads();

  // first zero position == number of leading ones
  {
    if (mask[b * SEQ + t] == 0)       atomicMin(&s_len, t);
    if (mask[b * SEQ + t + 256] == 0) atomicMin(&s_len, t + 256);
  }
  __syncthreads();
  const int len = s_len;
  const float lenf = (float)len;

#pragma unroll
  for (int p = 0; p < 3; ++p) {
    const int j = t + 256 * p;
    const unsigned n = (unsigned)(b * H + j);
    unsigned x0 = 0u, x1 = n;
    threefry_0_42(x0, x1);
    const unsigned bits = x0 ^ x1;
    const float u = __uint_as_float((bits >> 9) | 0x3f800000u) - 1.0f;
    int idx = (int)floorf(u * lenf);
    idx = min(idx, len - 1);
    emb[n] = tokens[(size_t)b * (SEQ * H) + (size_t)idx * H + j];
  }
}

// ---------------- Kernel 2: tiled triple-GEMM + tanh-energy partials ------
// T = cls@Wtop, U0 = cls@Wbot, U1 = emb@Wbot computed per 32x32 tile in one
// k-loop; then e0_partial[b] += sum_n v*tanh(T+U0+bias),
//              e1_partial[b] += sum_n v*tanh(T+U1+bias)  via atomicAdd.
#define TM 32
#define TN 32
#define BKK 32
#define PAD 2
__global__ __launch_bounds__(256) void gemm_fused_kernel(
    const float* __restrict__ cls,      // [BS, H]
    const float* __restrict__ emb,      // [BS, H] (ws)
    const float* __restrict__ W,        // [2H, H]
    const float* __restrict__ bias,     // [H]
    const float* __restrict__ v,        // [H]
    float* __restrict__ ge0,            // [BS]
    float* __restrict__ ge1)            // [BS]
{
  __shared__ float s_c [BKK][TM + PAD];
  __shared__ float s_e [BKK][TM + PAD];
  __shared__ float s_wt[BKK][TN + PAD];
  __shared__ float s_wb[BKK][TN + PAD];

  const int n0 = blockIdx.x * TN;       // column tile (hidden out)
  const int m0 = blockIdx.y * TM;       // batch tile
  const int t  = threadIdx.x;
  const int tx = t & 15;                // 2 cols each
  const int ty = t >> 4;                // 2 rows each

  const float* __restrict__ Wt = W;
  const float* __restrict__ Wb = W + (size_t)H * H;

  float aT[2][2] = {};
  float a0[2][2] = {};
  float a1[2][2] = {};

  const int lk = t & 31, lr = t >> 5;   // staging: 8 rows per pass

  for (int kk = 0; kk < H; kk += BKK) {
#pragma unroll
    for (int p = 0; p < 4; ++p) {
      const int r = lr + 8 * p;
      s_c[lk][r]  = cls[(size_t)(m0 + r) * H + kk + lk];
      s_e[lk][r]  = emb[(size_t)(m0 + r) * H + kk + lk];
      s_wt[r][lk] = Wt[(size_t)(kk + r) * H + n0 + lk];
      s_wb[r][lk] = Wb[(size_t)(kk + r) * H + n0 + lk];
    }
    __syncthreads();
#pragma unroll
    for (int k = 0; k < BKK; ++k) {
      const float2 c  = *(const float2*)&s_c [k][2 * ty];
      const float2 e  = *(const float2*)&s_e [k][2 * ty];
      const float2 wt = *(const float2*)&s_wt[k][2 * tx];
      const float2 wb = *(const float2*)&s_wb[k][2 * tx];
      aT[0][0] = fmaf(c.x, wt.x, aT[0][0]);
      aT[0][1] = fmaf(c.x, wt.y, aT[0][1]);
      aT[1][0] = fmaf(c.y, wt.x, aT[1][0]);
      aT[1][1] = fmaf(c.y, wt.y, aT[1][1]);
      a0[0][0] = fmaf(c.x, wb.x, a0[0][0]);
      a0[0][1] = fmaf(c.x, wb.y, a0[0][1]);
      a0[1][0] = fmaf(c.y, wb.x, a0[1][0]);
      a0[1][1] = fmaf(c.y, wb.y, a0[1][1]);
      a1[0][0] = fmaf(e.x, wb.x, a1[0][0]);
      a1[0][1] = fmaf(e.x, wb.y, a1[0][1]);
      a1[1][0] = fmaf(e.y, wb.x, a1[1][0]);
      a1[1][1] = fmaf(e.y, wb.y, a1[1][1]);
    }
    __syncthreads();
  }

  // energy partials over this block's 32 columns
  float p0[2] = {0.0f, 0.0f};
  float p1[2] = {0.0f, 0.0f};
#pragma unroll
  for (int j = 0; j < 2; ++j) {
    const int n = n0 + 2 * tx + j;
    const float bb = bias[n];
    const float vv = v[n];
#pragma unroll
    for (int i = 0; i < 2; ++i) {
      p0[i] += vv * tanhf(aT[i][j] + a0[i][j] + bb);
      p1[i] += vv * tanhf(aT[i][j] + a1[i][j] + bb);
    }
  }
  // reduce across the 16 tx lanes (decreasing offsets keep the cone in-group)
#pragma unroll
  for (int off = 8; off > 0; off >>= 1) {
#pragma unroll
    for (int i = 0; i < 2; ++i) {
      p0[i] += __shfl_down(p0[i], off);
      p1[i] += __shfl_down(p1[i], off);
    }
  }
  if (tx == 0) {
#pragma unroll
    for (int i = 0; i < 2; ++i) {
      atomicAdd(&ge0[m0 + 2 * ty + i], p0[i]);
      atomicAdd(&ge1[m0 + 2 * ty + i], p1[i]);
    }
  }
}

// ---------------- Kernel 3: softmax(2) + blend ----------------------------
__global__ __launch_bounds__(256) void blend_kernel(
    const float* __restrict__ cls,
    const float* __restrict__ emb,
    const float* __restrict__ ge0,
    const float* __restrict__ ge1,
    float* __restrict__ out)
{
  const int b = blockIdx.x;
  const int t = threadIdx.x;

  __shared__ float s_a0, s_a1;
  if (t == 0) {
    const float e0 = ge0[b], e1 = ge1[b];
    const float mx = fmaxf(e0, e1);
    const float x0 = expf(e0 - mx), x1 = expf(e1 - mx);
    const float inv = 1.0f / (x0 + x1);
    s_a0 = x0 * inv; s_a1 = x1 * inv;
  }
  __syncthreads();
  const float a0 = s_a0, a1 = s_a1;
#pragma unroll
  for (int p = 0; p < 3; ++p) {
    const int j = t + 256 * p;
    out[b * H + j] = a0 * cls[b * H + j] + a1 * emb[b * H + j];
  }
}

// ---------------------------------------------------------------------------
extern "C" void kernel_launch(void* const* d_in, const int* in_sizes, int n_in,
                              void* d_out, int out_size, void* d_ws, size_t ws_size,
                              hipStream_t stream) {
  const float* tokens = (const float*)d_in[0];   // [256,512,768] f32
  const float* cls    = (const float*)d_in[1];   // [256,768] f32
  const int*   mask   = (const int*)  d_in[2];   // [256,512] i32
  const float* W      = (const float*)d_in[3];   // [1536,768] f32
  const float* bias   = (const float*)d_in[4];   // [768] f32
  const float* v      = (const float*)d_in[5];   // [768] f32
  float* out = (float*)d_out;

  float* ws  = (float*)d_ws;
  float* emb = ws;                 // BS*H floats (786 KB)
  float* ge0 = ws + BS * H;        // BS floats
  float* ge1 = ge0 + BS;           // BS floats   (total < 0.8 MB)

  prep_kernel<<<BS, 256, 0, stream>>>(tokens, mask, emb, ge0, ge1);

  dim3 g(H / TN, BS / TM);         // 24 x 8 = 192 blocks
  gemm_fused_kernel<<<g, 256, 0, stream>>>(cls, emb, W, bias, v, ge0, ge1);

  blend_kernel<<<BS, 256, 0, stream>>>(cls, emb, ge0, ge1, out);
}